// Round 1
// baseline (2146.740 us; speedup 1.0000x reference)
//
#include <hip/hip_runtime.h>
#include <math.h>

#define NN 50000
#define NE 800000

__device__ __forceinline__ float sigm(float x){ return 1.f/(1.f+expf(-x)); }

// ---------- graph preprocessing ----------
__global__ __launch_bounds__(256) void k_init(float* deg,int* cnt,float* colsum,float* colsq){
  int i=blockIdx.x*256+threadIdx.x;
  if(i<NN){deg[i]=1.0f;cnt[i]=0;}   // deg starts at 1.0 = self-loop weight
  if(i<256){colsum[i]=0.f;colsq[i]=0.f;}
}

__global__ __launch_bounds__(256) void k_deg(const int* __restrict__ ei,const float* __restrict__ ew,
                                             float* deg,int* cnt){
  int e=blockIdx.x*256+threadIdx.x;
  if(e<NE){int d=ei[NE+e];atomicAdd(&deg[d],ew[e]);atomicAdd(&cnt[d],1);}
}

__global__ __launch_bounds__(256) void k_dinv(const float* __restrict__ deg,float* dinv){
  int i=blockIdx.x*256+threadIdx.x;
  if(i<NN){float d=deg[i];dinv[i]=d>0.f?rsqrtf(d):0.f;}
}

// single-block exclusive scan of cnt -> row_ptr (and cursor copy)
__global__ __launch_bounds__(1024) void k_scan(const int* __restrict__ cnt,int* row_ptr,int* cursor){
  __shared__ int s[1024];
  __shared__ int carry;
  int tid=threadIdx.x;
  if(tid==0)carry=0;
  __syncthreads();
  for(int base=0;base<NN;base+=1024){
    int i=base+tid;
    int v=(i<NN)?cnt[i]:0;
    s[tid]=v;__syncthreads();
    for(int off=1;off<1024;off<<=1){
      int t=(tid>=off)?s[tid-off]:0;
      __syncthreads();
      s[tid]+=t;__syncthreads();
    }
    int excl=carry+s[tid]-v;
    if(i<NN){row_ptr[i]=excl;cursor[i]=excl;}
    __syncthreads();
    if(tid==1023)carry+=s[1023];
    __syncthreads();
  }
  if(tid==0)row_ptr[NN]=carry;
}

__global__ __launch_bounds__(256) void k_scatter(const int* __restrict__ ei,const float* __restrict__ ew,
    const float* __restrict__ dinv,int* cursor,int* csr_src,float* csr_w){
  int e=blockIdx.x*256+threadIdx.x;
  if(e<NE){
    int s=ei[e],d=ei[NE+e];
    float wv=dinv[s]*ew[e]*dinv[d];
    int p=atomicAdd(&cursor[d],1);
    csr_src[p]=s;csr_w[p]=wv;
  }
}

// ---------- dense GEMM: C[N,256] = A[N,256] @ W[256,256] ----------
__global__ __launch_bounds__(256) void k_gemm256(const float* __restrict__ A,int lda,
    const float* __restrict__ W,float* __restrict__ C,int ldc){
  __shared__ float At[16][68];
  __shared__ float Bs[16][68];
  int tid=threadIdx.x;
  int tx=tid&15,ty=tid>>4;
  int row0=blockIdx.x*64,col0=blockIdx.y*64;
  float acc[4][4]={};
  int lr=tid>>2,lk=(tid&3)*4;
  for(int k0=0;k0<256;k0+=16){
    float4 av=make_float4(0.f,0.f,0.f,0.f);
    int ar=row0+lr;
    if(ar<NN)av=*(const float4*)&A[(long)ar*lda+k0+lk];
    At[lk+0][lr]=av.x;At[lk+1][lr]=av.y;At[lk+2][lr]=av.z;At[lk+3][lr]=av.w;
    int bk=tid>>4,bj=(tid&15)*4;
    *(float4*)&Bs[bk][bj]=*(const float4*)&W[(k0+bk)*256+col0+bj];
    __syncthreads();
    #pragma unroll
    for(int k=0;k<16;k++){
      float4 a4=*(const float4*)&At[k][ty*4];
      float4 b4=*(const float4*)&Bs[k][tx*4];
      float a[4]={a4.x,a4.y,a4.z,a4.w};
      float b[4]={b4.x,b4.y,b4.z,b4.w};
      #pragma unroll
      for(int i=0;i<4;i++)
        #pragma unroll
        for(int j=0;j<4;j++)acc[i][j]+=a[i]*b[j];
    }
    __syncthreads();
  }
  #pragma unroll
  for(int i=0;i<4;i++){
    int r=row0+ty*4+i;
    if(r<NN){
      float4 v=make_float4(acc[i][0],acc[i][1],acc[i][2],acc[i][3]);
      *(float4*)&C[(long)r*ldc+col0+tx*4]=v;
    }
  }
}

// ---------- SpMM + self-loop + bias + ReLU + column stats ----------
__global__ __launch_bounds__(256) void k_spmm(const float* __restrict__ T,int ldt,
    const int* __restrict__ row_ptr,const int* __restrict__ csr_src,const float* __restrict__ csr_w,
    const float* __restrict__ dinv,const float* __restrict__ bias,
    float* __restrict__ Aout,int ldo,float* colsum,float* colsq){
  int c=threadIdx.x;               // column 0..255
  int n0=blockIdx.x*64;
  int n1=min(n0+64,NN);
  float bc=bias[c];
  float lsum=0.f,lsq=0.f;
  for(int i=n0;i<n1;i++){
    float di=dinv[i];
    float acc=di*di*T[(long)i*ldt+c];           // self-loop: norm = dinv*1*dinv
    int p0=row_ptr[i],p1=row_ptr[i+1];
    for(int p=p0;p<p1;p++){
      acc+=csr_w[p]*T[(long)csr_src[p]*ldt+c];
    }
    acc+=bc;
    acc=fmaxf(acc,0.f);
    Aout[(long)i*ldo+c]=acc;
    lsum+=acc;lsq+=acc*acc;
  }
  atomicAdd(&colsum[c],lsum);
  atomicAdd(&colsq[c],lsq);
}

// ---------- BN finalize: scale/shift, then re-zero sums for next layer ----------
__global__ __launch_bounds__(256) void k_bnfin(const float* __restrict__ gamma,const float* __restrict__ beta,
    float* colsum,float* colsq,float* scale,float* shift){
  int c=threadIdx.x;
  float mu=colsum[c]/(float)NN;
  float var=colsq[c]/(float)NN-mu*mu;
  float r=rsqrtf(var+1e-5f);
  float sc=r*gamma[c];
  scale[c]=sc;
  shift[c]=beta[c]-mu*sc;
  colsum[c]=0.f;colsq[c]=0.f;
}

__global__ __launch_bounds__(256) void k_bnapply(float* __restrict__ H,int ldh,
    const float* __restrict__ scale,const float* __restrict__ shift){
  long idx=(long)blockIdx.x*256+threadIdx.x;
  long r=idx>>6;int cc=(int)(idx&63)*4;
  if(r<NN){
    float4 v=*(float4*)&H[r*ldh+cc];
    v.x=v.x*scale[cc+0]+shift[cc+0];
    v.y=v.y*scale[cc+1]+shift[cc+1];
    v.z=v.z*scale[cc+2]+shift[cc+2];
    v.w=v.w*scale[cc+3]+shift[cc+3];
    *(float4*)&H[r*ldh+cc]=v;
  }
}

// ---------- LSTM step-0 fused GEMM: h = sig(o)*tanh(sig(i)*tanh(g)) ----------
// gates = A @ Wih^T + bih + bhh ; f-gate skipped (c0=0). Computes 3 gate tiles.
template<int K>
__global__ __launch_bounds__(256) void k_lstm(const float* __restrict__ A,int lda,
    const float* __restrict__ Wih,const float* __restrict__ bih,const float* __restrict__ bhh,
    float* __restrict__ Hout,int ldh){
  __shared__ float At[16][68];
  __shared__ float Bi[16][68];
  __shared__ float Bg[16][68];
  __shared__ float Bo[16][68];
  int tid=threadIdx.x;
  int tx=tid&15,ty=tid>>4;
  int row0=blockIdx.x*64,m0=blockIdx.y*64;
  float ai[4][4]={},ag[4][4]={},ao[4][4]={};
  int lr=tid>>2,lk=(tid&3)*4;
  for(int k0=0;k0<K;k0+=16){
    float4 av=make_float4(0.f,0.f,0.f,0.f);
    int ar=row0+lr;
    if(ar<NN)av=*(const float4*)&A[(long)ar*lda+k0+lk];
    At[lk+0][lr]=av.x;At[lk+1][lr]=av.y;At[lk+2][lr]=av.z;At[lk+3][lr]=av.w;
    float4 bv=*(const float4*)&Wih[(long)(m0+lr)*K+k0+lk];
    Bi[lk+0][lr]=bv.x;Bi[lk+1][lr]=bv.y;Bi[lk+2][lr]=bv.z;Bi[lk+3][lr]=bv.w;
    bv=*(const float4*)&Wih[(long)(512+m0+lr)*K+k0+lk];
    Bg[lk+0][lr]=bv.x;Bg[lk+1][lr]=bv.y;Bg[lk+2][lr]=bv.z;Bg[lk+3][lr]=bv.w;
    bv=*(const float4*)&Wih[(long)(768+m0+lr)*K+k0+lk];
    Bo[lk+0][lr]=bv.x;Bo[lk+1][lr]=bv.y;Bo[lk+2][lr]=bv.z;Bo[lk+3][lr]=bv.w;
    __syncthreads();
    #pragma unroll
    for(int k=0;k<16;k++){
      float4 a4=*(const float4*)&At[k][ty*4];
      float4 vi=*(const float4*)&Bi[k][tx*4];
      float4 vg=*(const float4*)&Bg[k][tx*4];
      float4 vo=*(const float4*)&Bo[k][tx*4];
      float a[4]={a4.x,a4.y,a4.z,a4.w};
      float bi_[4]={vi.x,vi.y,vi.z,vi.w};
      float bg_[4]={vg.x,vg.y,vg.z,vg.w};
      float bo_[4]={vo.x,vo.y,vo.z,vo.w};
      #pragma unroll
      for(int i=0;i<4;i++)
        #pragma unroll
        for(int j=0;j<4;j++){
          ai[i][j]+=a[i]*bi_[j];
          ag[i][j]+=a[i]*bg_[j];
          ao[i][j]+=a[i]*bo_[j];
        }
    }
    __syncthreads();
  }
  #pragma unroll
  for(int i=0;i<4;i++){
    int n=row0+ty*4+i;
    if(n>=NN)continue;
    float h4[4];
    #pragma unroll
    for(int j=0;j<4;j++){
      int m=m0+tx*4+j;
      float gi=ai[i][j]+bih[m]+bhh[m];
      float gg=ag[i][j]+bih[512+m]+bhh[512+m];
      float go=ao[i][j]+bih[768+m]+bhh[768+m];
      float cc=sigm(gi)*tanhf(gg);
      h4[j]=sigm(go)*tanhf(cc);
    }
    float4 v=make_float4(h4[0],h4[1],h4[2],h4[3]);
    *(float4*)&Hout[(long)n*ldh+m0+tx*4]=v;
  }
}

// ---------- copy [N,256] (ld 256) into out columns [colofs, colofs+256) ----------
__global__ __launch_bounds__(256) void k_copy_out(const float* __restrict__ src,
    float* __restrict__ out,int colofs){
  long idx=(long)blockIdx.x*256+threadIdx.x;
  long r=idx>>6;int cc=(int)(idx&63)*4;
  if(r<NN)*(float4*)&out[r*768+colofs+cc]=*(const float4*)&src[r*256+cc];
}

extern "C" void kernel_launch(void* const* d_in,const int* in_sizes,int n_in,
                              void* d_out,int out_size,void* d_ws,size_t ws_size,
                              hipStream_t stream){
  const float* x   =(const float*)d_in[0];
  const int*   ei  =(const int*)  d_in[1];
  const float* ew  =(const float*)d_in[2];
  const float* W1  =(const float*)d_in[3];
  const float* b1  =(const float*)d_in[4];
  const float* W2  =(const float*)d_in[5];
  const float* b2  =(const float*)d_in[6];
  const float* g1  =(const float*)d_in[7];
  const float* be1 =(const float*)d_in[8];
  const float* g2  =(const float*)d_in[9];
  const float* be2 =(const float*)d_in[10];
  const float* Wih1=(const float*)d_in[11];
  const float* bih1=(const float*)d_in[13];
  const float* bhh1=(const float*)d_in[14];
  const float* Wih2=(const float*)d_in[15];
  const float* bih2=(const float*)d_in[17];
  const float* bhh2=(const float*)d_in[18];
  float* out=(float*)d_out;

  char* w=(char*)d_ws;
  auto alloc=[&](size_t bytes)->char*{char* p=w;w+=(bytes+255)&~(size_t)255;return p;};
  float* deg    =(float*)alloc((size_t)NN*4);
  float* dinv   =(float*)alloc((size_t)NN*4);
  int*   cnt    =(int*)  alloc((size_t)NN*4);
  int*   row_ptr=(int*)  alloc((size_t)(NN+1)*4);
  int*   cursor =(int*)  alloc((size_t)NN*4);
  int*   csr_src=(int*)  alloc((size_t)NE*4);
  float* csr_w  =(float*)alloc((size_t)NE*4);
  float* colsum =(float*)alloc(256*4);
  float* colsq  =(float*)alloc(256*4);
  float* scale  =(float*)alloc(256*4);
  float* shift  =(float*)alloc(256*4);
  float* hL1    =(float*)alloc((size_t)NN*256*4);

  int nb=(NN+255)/256;
  k_init<<<nb,256,0,stream>>>(deg,cnt,colsum,colsq);
  k_deg<<<(NE+255)/256,256,0,stream>>>(ei,ew,deg,cnt);
  k_dinv<<<nb,256,0,stream>>>(deg,dinv);
  k_scan<<<1,1024,0,stream>>>(cnt,row_ptr,cursor);
  k_scatter<<<(NE+255)/256,256,0,stream>>>(ei,ew,dinv,cursor,csr_src,csr_w);

  dim3 gg((NN+63)/64,4);
  int nspmm=(NN+63)/64;
  // layer 1: t0 = x@W1 -> out cols [512:768); SpMM -> out cols [0:256)
  k_gemm256<<<gg,256,0,stream>>>(x,256,W1,out+512,768);
  k_spmm<<<nspmm,256,0,stream>>>(out+512,768,row_ptr,csr_src,csr_w,dinv,b1,out+0,768,colsum,colsq);
  k_bnfin<<<1,256,0,stream>>>(g1,be1,colsum,colsq,scale,shift);
  k_bnapply<<<12500,256,0,stream>>>(out+0,768,scale,shift);
  // layer 2: t1 = h1n@W2 -> out cols [512:768); SpMM -> out cols [256:512)
  k_gemm256<<<gg,256,0,stream>>>(out+0,768,W2,out+512,768);
  k_spmm<<<nspmm,256,0,stream>>>(out+512,768,row_ptr,csr_src,csr_w,dinv,b2,out+256,768,colsum,colsq);
  k_bnfin<<<1,256,0,stream>>>(g2,be2,colsum,colsq,scale,shift);
  k_bnapply<<<12500,256,0,stream>>>(out+256,768,scale,shift);
  // LSTM1: Xc = out cols [0:512) (contiguous h1|h2 per row), K=512 -> ws (avoid RAW race)
  k_lstm<512><<<gg,256,0,stream>>>(out+0,768,Wih1,bih1,bhh1,hL1,256);
  k_copy_out<<<12500,256,0,stream>>>(hL1,out,0);
  // LSTM2: reads hL1 (ws), K=256 -> out cols [256:512)
  k_lstm<256><<<gg,256,0,stream>>>(hL1,256,Wih2,bih2,bhh2,out+256,768);
  // x passthrough -> out cols [512:768)
  k_copy_out<<<12500,256,0,stream>>>(x,out,512);
}

// Round 2
// 1395.809 us; speedup vs baseline: 1.5380x; 1.5380x over previous
//
#include <hip/hip_runtime.h>
#include <math.h>

#define NN 50000
#define NE 800000
#define LDP 40   // LDS tile row pitch in bf16 (32 data + 8 pad -> 80B, 16B-aligned, conflict-benign)

typedef __attribute__((ext_vector_type(8))) short bf8;   // 8 bf16 = 4 VGPRs (MFMA A/B frag)
typedef __attribute__((ext_vector_type(4))) float f32x4; // MFMA C/D frag

__device__ __forceinline__ float sigm(float x){ return 1.f/(1.f+expf(-x)); }
__device__ __forceinline__ unsigned short f2b(float f){
  union{float f;unsigned u;} v; v.f=f;
  unsigned r=v.u+0x7fff+((v.u>>16)&1u);
  return (unsigned short)(r>>16);
}

// ---------- graph preprocessing ----------
__global__ __launch_bounds__(256) void k_init(float* deg,int* cnt,float* colsum,float* colsq){
  int i=blockIdx.x*256+threadIdx.x;
  if(i<NN){deg[i]=1.0f;cnt[i]=0;}
  if(i<256){colsum[i]=0.f;colsq[i]=0.f;}
}

__global__ __launch_bounds__(256) void k_deg(const int* __restrict__ ei,const float* __restrict__ ew,
                                             float* deg,int* cnt){
  int e=blockIdx.x*256+threadIdx.x;
  if(e<NE){int d=ei[NE+e];atomicAdd(&deg[d],ew[e]);atomicAdd(&cnt[d],1);}
}

__global__ __launch_bounds__(256) void k_dinv(const float* __restrict__ deg,float* dinv){
  int i=blockIdx.x*256+threadIdx.x;
  if(i<NN){float d=deg[i];dinv[i]=d>0.f?rsqrtf(d):0.f;}
}

__global__ __launch_bounds__(1024) void k_scan(const int* __restrict__ cnt,int* row_ptr,int* cursor){
  __shared__ int s[1024];
  __shared__ int carry;
  int tid=threadIdx.x;
  if(tid==0)carry=0;
  __syncthreads();
  for(int base=0;base<NN;base+=1024){
    int i=base+tid;
    int v=(i<NN)?cnt[i]:0;
    s[tid]=v;__syncthreads();
    for(int off=1;off<1024;off<<=1){
      int t=(tid>=off)?s[tid-off]:0;
      __syncthreads();
      s[tid]+=t;__syncthreads();
    }
    int excl=carry+s[tid]-v;
    if(i<NN){row_ptr[i]=excl;cursor[i]=excl;}
    __syncthreads();
    if(tid==1023)carry+=s[1023];
    __syncthreads();
  }
  if(tid==0)row_ptr[NN]=carry;
}

__global__ __launch_bounds__(256) void k_scatter(const int* __restrict__ ei,const float* __restrict__ ew,
    const float* __restrict__ dinv,int* cursor,int* csr_src,float* csr_w){
  int e=blockIdx.x*256+threadIdx.x;
  if(e<NE){
    int s=ei[e],d=ei[NE+e];
    float wv=dinv[s]*ew[e]*dinv[d];
    int p=atomicAdd(&cursor[d],1);
    csr_src[p]=s;csr_w[p]=wv;
  }
}

// ---------- weight prep ----------
// W [256,256] fp32 (k-major) -> Wt [256,256] bf16 transposed: Wt[j][k]=W[k][j]
__global__ __launch_bounds__(256) void k_wt(const float* __restrict__ W,unsigned short* __restrict__ Wt){
  int j=blockIdx.x,k=threadIdx.x;
  Wt[j*256+k]=f2b(W[k*256+j]);
}
__global__ __launch_bounds__(256) void k_f2b(const float* __restrict__ s,unsigned short* __restrict__ d,int n){
  int i=blockIdx.x*256+threadIdx.x;
  if(i<n)d[i]=f2b(s[i]);
}
__global__ __launch_bounds__(256) void k_bsum(const float* __restrict__ a,const float* __restrict__ b,
                                              float* __restrict__ s,int n){
  int i=blockIdx.x*256+threadIdx.x;
  if(i<n)s[i]=a[i]+b[i];
}

// ---------- dense MFMA GEMM: C[M,256] = A[M,K] @ Bt^T  (Bt is [N][K] bf16) ----------
template<typename TA>
__global__ __launch_bounds__(256,2) void k_gemm_mfma(
    const TA* __restrict__ A,int lda,const unsigned short* __restrict__ Bt,int K,
    float* __restrict__ C,int ldc){
  __shared__ unsigned short As[128*LDP];
  __shared__ unsigned short Bs[128*LDP];
  int tid=threadIdx.x;
  int row0=blockIdx.x*128,col0=blockIdx.y*128;
  int lane=tid&63,l15=lane&15,quad=lane>>4;
  int wid=tid>>6,wm=wid>>1,wn=wid&1;
  f32x4 acc[4][4]={};
  for(int k0=0;k0<K;k0+=32){
    if constexpr(sizeof(TA)==4){
      int r=tid>>3,ks=(tid&7)*4;
      #pragma unroll
      for(int rr=0;rr<4;rr++){
        int row=row0+rr*32+r;
        float4 v=make_float4(0.f,0.f,0.f,0.f);
        if(row<NN)v=*(const float4*)&A[(long)row*lda+k0+ks];
        ushort4 h;h.x=f2b(v.x);h.y=f2b(v.y);h.z=f2b(v.z);h.w=f2b(v.w);
        *(ushort4*)&As[(rr*32+r)*LDP+ks]=h;
      }
    }else{
      int r=tid>>2,ks=(tid&3)*8;
      #pragma unroll
      for(int rr=0;rr<2;rr++){
        int row=row0+rr*64+r;
        bf8 v=(bf8)(short)0;
        if(row<NN)v=*(const bf8*)&A[(long)row*lda+k0+ks];
        *(bf8*)&As[(rr*64+r)*LDP+ks]=v;
      }
    }
    { int r=tid>>2,ks=(tid&3)*8;
      #pragma unroll
      for(int rr=0;rr<2;rr++){
        bf8 v=*(const bf8*)&Bt[(long)(col0+rr*64+r)*K+k0+ks];
        *(bf8*)&Bs[(rr*64+r)*LDP+ks]=v;
      }
    }
    __syncthreads();
    bf8 af[4],bfg[4];
    #pragma unroll
    for(int i=0;i<4;i++){
      af[i]=*(const bf8*)&As[(wm*64+i*16+l15)*LDP+quad*8];
      bfg[i]=*(const bf8*)&Bs[(wn*64+i*16+l15)*LDP+quad*8];
    }
    #pragma unroll
    for(int mi=0;mi<4;mi++)
      #pragma unroll
      for(int ni=0;ni<4;ni++)
        acc[mi][ni]=__builtin_amdgcn_mfma_f32_16x16x32_bf16(af[mi],bfg[ni],acc[mi][ni],0,0,0);
    __syncthreads();
  }
  #pragma unroll
  for(int mi=0;mi<4;mi++){
    #pragma unroll
    for(int r=0;r<4;r++){
      int node=row0+wm*64+mi*16+quad*4+r;
      if(node>=NN)continue;
      #pragma unroll
      for(int ni=0;ni<4;ni++){
        int col=col0+wn*64+ni*16+l15;
        C[(long)node*ldc+col]=acc[mi][ni][r];
      }
    }
  }
}

// ---------- fused 3-gate LSTM MFMA: h = sig(o)*tanh(sig(i)*tanh(g)) ----------
// Wb is bf16 Wih [1024][K] row-major; gates i,g,o at row offsets 0,512,768.
__global__ __launch_bounds__(256,2) void k_lstm_mfma(
    const unsigned short* __restrict__ A,int lda,int K,
    const unsigned short* __restrict__ Wb,const float* __restrict__ bsum,
    float* __restrict__ Hout,int ldh,unsigned short* __restrict__ Hb){
  __shared__ unsigned short As[128*LDP];
  __shared__ unsigned short Bs[3*64*LDP];
  int tid=threadIdx.x;
  int row0=blockIdx.x*128,m0=blockIdx.y*64;
  int lane=tid&63,l15=lane&15,quad=lane>>4;
  int wid=tid>>6,wm=wid>>1,wn=wid&1;
  f32x4 ai[4][2]={},ag[4][2]={},ao[4][2]={};
  for(int k0=0;k0<K;k0+=32){
    { int r=tid>>2,ks=(tid&3)*8;
      #pragma unroll
      for(int rr=0;rr<2;rr++){
        int row=row0+rr*64+r;
        bf8 v=(bf8)(short)0;
        if(row<NN)v=*(const bf8*)&A[(long)row*lda+k0+ks];
        *(bf8*)&As[(rr*64+r)*LDP+ks]=v;
      }
      bf8 v0=*(const bf8*)&Wb[(long)(  0+m0+r)*K+k0+ks];
      bf8 v1=*(const bf8*)&Wb[(long)(512+m0+r)*K+k0+ks];
      bf8 v2=*(const bf8*)&Wb[(long)(768+m0+r)*K+k0+ks];
      *(bf8*)&Bs[(0*64+r)*LDP+ks]=v0;
      *(bf8*)&Bs[(1*64+r)*LDP+ks]=v1;
      *(bf8*)&Bs[(2*64+r)*LDP+ks]=v2;
    }
    __syncthreads();
    bf8 af[4],bi[2],bg[2],bo[2];
    #pragma unroll
    for(int i=0;i<4;i++)af[i]=*(const bf8*)&As[(wm*64+i*16+l15)*LDP+quad*8];
    #pragma unroll
    for(int ni=0;ni<2;ni++){
      int rr=wn*32+ni*16+l15;
      bi[ni]=*(const bf8*)&Bs[(0*64+rr)*LDP+quad*8];
      bg[ni]=*(const bf8*)&Bs[(1*64+rr)*LDP+quad*8];
      bo[ni]=*(const bf8*)&Bs[(2*64+rr)*LDP+quad*8];
    }
    #pragma unroll
    for(int mi=0;mi<4;mi++)
      #pragma unroll
      for(int ni=0;ni<2;ni++){
        ai[mi][ni]=__builtin_amdgcn_mfma_f32_16x16x32_bf16(af[mi],bi[ni],ai[mi][ni],0,0,0);
        ag[mi][ni]=__builtin_amdgcn_mfma_f32_16x16x32_bf16(af[mi],bg[ni],ag[mi][ni],0,0,0);
        ao[mi][ni]=__builtin_amdgcn_mfma_f32_16x16x32_bf16(af[mi],bo[ni],ao[mi][ni],0,0,0);
      }
    __syncthreads();
  }
  #pragma unroll
  for(int ni=0;ni<2;ni++){
    int m=m0+wn*32+ni*16+l15;
    float b_i=bsum[m],b_g=bsum[512+m],b_o=bsum[768+m];
    #pragma unroll
    for(int mi=0;mi<4;mi++){
      #pragma unroll
      for(int r=0;r<4;r++){
        int node=row0+wm*64+mi*16+quad*4+r;
        if(node>=NN)continue;
        float gi=ai[mi][ni][r]+b_i;
        float gg=ag[mi][ni][r]+b_g;
        float go=ao[mi][ni][r]+b_o;
        float c=sigm(gi)*tanhf(gg);
        float h=sigm(go)*tanhf(c);
        Hout[(long)node*ldh+m]=h;
        if(Hb)Hb[(long)node*256+m]=f2b(h);
      }
    }
  }
}

// ---------- SpMM + self-loop + bias + ReLU + column stats ----------
__global__ __launch_bounds__(256) void k_spmm(const float* __restrict__ T,int ldt,
    const int* __restrict__ row_ptr,const int* __restrict__ csr_src,const float* __restrict__ csr_w,
    const float* __restrict__ dinv,const float* __restrict__ bias,
    float* __restrict__ Aout,int ldo,float* colsum,float* colsq){
  int c=threadIdx.x;
  int n0=blockIdx.x*64;
  int n1=min(n0+64,NN);
  float bc=bias[c];
  float lsum=0.f,lsq=0.f;
  for(int i=n0;i<n1;i++){
    float di=dinv[i];
    float acc=di*di*T[(long)i*ldt+c];
    int p0=row_ptr[i],p1=row_ptr[i+1];
    for(int p=p0;p<p1;p++){
      acc+=csr_w[p]*T[(long)csr_src[p]*ldt+c];
    }
    acc+=bc;
    acc=fmaxf(acc,0.f);
    Aout[(long)i*ldo+c]=acc;
    lsum+=acc;lsq+=acc*acc;
  }
  atomicAdd(&colsum[c],lsum);
  atomicAdd(&colsq[c],lsq);
}

__global__ __launch_bounds__(256) void k_bnfin(const float* __restrict__ gamma,const float* __restrict__ beta,
    float* colsum,float* colsq,float* scale,float* shift){
  int c=threadIdx.x;
  float mu=colsum[c]/(float)NN;
  float var=colsq[c]/(float)NN-mu*mu;
  float r=rsqrtf(var+1e-5f);
  float sc=r*gamma[c];
  scale[c]=sc;
  shift[c]=beta[c]-mu*sc;
  colsum[c]=0.f;colsq[c]=0.f;
}

// BN affine, fp32 in (ld 768) -> bf16 out into Xcb column slab [cofs, cofs+256)
__global__ __launch_bounds__(256) void k_bnapply(const float* __restrict__ H,
    const float* __restrict__ scale,const float* __restrict__ shift,
    unsigned short* __restrict__ Xb,int cofs){
  long idx=(long)blockIdx.x*256+threadIdx.x;
  long r=idx>>6;int c=(int)(idx&63)*4;
  if(r<NN){
    float4 v=*(const float4*)&H[r*768+c];
    ushort4 w;
    w.x=f2b(v.x*scale[c+0]+shift[c+0]);
    w.y=f2b(v.y*scale[c+1]+shift[c+1]);
    w.z=f2b(v.z*scale[c+2]+shift[c+2]);
    w.w=f2b(v.w*scale[c+3]+shift[c+3]);
    *(ushort4*)&Xb[r*512+cofs+c]=w;
  }
}

// copy [N,256] fp32 (ld 256) into out columns [colofs, colofs+256)
__global__ __launch_bounds__(256) void k_copy_out(const float* __restrict__ src,
    float* __restrict__ out,int colofs){
  long idx=(long)blockIdx.x*256+threadIdx.x;
  long r=idx>>6;int cc=(int)(idx&63)*4;
  if(r<NN)*(float4*)&out[r*768+colofs+cc]=*(const float4*)&src[r*256+cc];
}

extern "C" void kernel_launch(void* const* d_in,const int* in_sizes,int n_in,
                              void* d_out,int out_size,void* d_ws,size_t ws_size,
                              hipStream_t stream){
  const float* x   =(const float*)d_in[0];
  const int*   ei  =(const int*)  d_in[1];
  const float* ew  =(const float*)d_in[2];
  const float* W1  =(const float*)d_in[3];
  const float* b1  =(const float*)d_in[4];
  const float* W2  =(const float*)d_in[5];
  const float* b2  =(const float*)d_in[6];
  const float* g1  =(const float*)d_in[7];
  const float* be1 =(const float*)d_in[8];
  const float* g2  =(const float*)d_in[9];
  const float* be2 =(const float*)d_in[10];
  const float* Wih1=(const float*)d_in[11];
  const float* bih1=(const float*)d_in[13];
  const float* bhh1=(const float*)d_in[14];
  const float* Wih2=(const float*)d_in[15];
  const float* bih2=(const float*)d_in[17];
  const float* bhh2=(const float*)d_in[18];
  float* out=(float*)d_out;

  char* w=(char*)d_ws;
  auto alloc=[&](size_t bytes)->char*{char* p=w;w+=(bytes+255)&~(size_t)255;return p;};
  float* deg    =(float*)alloc((size_t)NN*4);
  float* dinv   =(float*)alloc((size_t)NN*4);
  int*   cnt    =(int*)  alloc((size_t)NN*4);
  int*   row_ptr=(int*)  alloc((size_t)(NN+1)*4);
  int*   cursor =(int*)  alloc((size_t)NN*4);
  int*   csr_src=(int*)  alloc((size_t)NE*4);
  float* csr_w  =(float*)alloc((size_t)NE*4);
  float* colsum =(float*)alloc(256*4);
  float* colsq  =(float*)alloc(256*4);
  float* scale  =(float*)alloc(256*4);
  float* shift  =(float*)alloc(256*4);
  unsigned short* Xcb =(unsigned short*)alloc((size_t)NN*512*2);  // [h1n|h2n] bf16
  unsigned short* hL1b=(unsigned short*)alloc((size_t)NN*256*2);  // LSTM1 hidden bf16
  unsigned short* Wt1 =(unsigned short*)alloc(256*256*2);
  unsigned short* Wt2 =(unsigned short*)alloc(256*256*2);
  unsigned short* Wb1 =(unsigned short*)alloc((size_t)1024*512*2);
  unsigned short* Wb2 =(unsigned short*)alloc((size_t)1024*256*2);
  float* bs1 =(float*)alloc(1024*4);
  float* bs2 =(float*)alloc(1024*4);

  int nb=(NN+255)/256;
  k_init<<<nb,256,0,stream>>>(deg,cnt,colsum,colsq);
  k_deg<<<(NE+255)/256,256,0,stream>>>(ei,ew,deg,cnt);
  k_dinv<<<nb,256,0,stream>>>(deg,dinv);
  k_scan<<<1,1024,0,stream>>>(cnt,row_ptr,cursor);
  k_scatter<<<(NE+255)/256,256,0,stream>>>(ei,ew,dinv,cursor,csr_src,csr_w);

  // weight prep (bf16)
  k_wt<<<256,256,0,stream>>>(W1,Wt1);
  k_wt<<<256,256,0,stream>>>(W2,Wt2);
  k_f2b<<<(1024*512+255)/256,256,0,stream>>>(Wih1,Wb1,1024*512);
  k_f2b<<<(1024*256+255)/256,256,0,stream>>>(Wih2,Wb2,1024*256);
  k_bsum<<<4,256,0,stream>>>(bih1,bhh1,bs1,1024);
  k_bsum<<<4,256,0,stream>>>(bih2,bhh2,bs2,1024);

  int ngx=(NN+127)/128;
  dim3 gd(ngx,2);   // dense: N=256
  dim3 gl(ngx,4);   // lstm:  256 h-cols / 64
  int nspmm=(NN+63)/64;

  // layer 1: t = x@W1 -> out[512:768); spmm -> pre-BN h1 at out[0:256); BN -> Xcb[:,0:256)
  k_gemm_mfma<float><<<gd,256,0,stream>>>(x,256,Wt1,256,out+512,768);
  k_spmm<<<nspmm,256,0,stream>>>(out+512,768,row_ptr,csr_src,csr_w,dinv,b1,out+0,768,colsum,colsq);
  k_bnfin<<<1,256,0,stream>>>(g1,be1,colsum,colsq,scale,shift);
  k_bnapply<<<12500,256,0,stream>>>(out+0,scale,shift,Xcb,0);
  // layer 2
  k_gemm_mfma<unsigned short><<<gd,256,0,stream>>>(Xcb,512,Wt2,256,out+512,768);
  k_spmm<<<nspmm,256,0,stream>>>(out+512,768,row_ptr,csr_src,csr_w,dinv,b2,out+256,768,colsum,colsq);
  k_bnfin<<<1,256,0,stream>>>(g2,be2,colsum,colsq,scale,shift);
  k_bnapply<<<12500,256,0,stream>>>(out+256,scale,shift,Xcb,256);
  // LSTM1: A=Xcb [N,512] -> hL1 fp32 into out[0:256) (+bf16 copy); overwrites dead pre-BN h1
  k_lstm_mfma<<<gl,256,0,stream>>>(Xcb,512,512,Wb1,bs1,out+0,768,hL1b);
  // LSTM2: A=hL1b [N,256] -> out[256:512)
  k_lstm_mfma<<<gl,256,0,stream>>>(hL1b,256,256,Wb2,bs2,out+256,768,nullptr);
  // x passthrough
  k_copy_out<<<12500,256,0,stream>>>(x,out,512);
}

// Round 3
// 922.315 us; speedup vs baseline: 2.3276x; 1.5134x over previous
//
#include <hip/hip_runtime.h>
#include <math.h>

#define NN 50000
#define NE 800000
#define LDP 40   // LDS tile row pitch in bf16

typedef __attribute__((ext_vector_type(8))) short bf8;   // 8 bf16 = 4 VGPRs (MFMA A/B frag)
typedef __attribute__((ext_vector_type(4))) float f32x4; // MFMA C/D frag

__device__ __forceinline__ float sigm(float x){ return 1.f/(1.f+expf(-x)); }
__device__ __forceinline__ unsigned short f2b(float f){
  union{float f;unsigned u;} v; v.f=f;
  unsigned r=v.u+0x7fff+((v.u>>16)&1u);
  return (unsigned short)(r>>16);
}
__device__ __forceinline__ float b2f(unsigned short h){
  union{unsigned u;float f;} v; v.u=((unsigned)h)<<16; return v.f;
}

// ---------- graph preprocessing ----------
__global__ __launch_bounds__(256) void k_init(float* deg,int* cnt,float* colsum,float* colsq){
  int i=blockIdx.x*256+threadIdx.x;
  if(i<NN){deg[i]=1.0f;cnt[i]=0;}
  if(i<256){colsum[i]=0.f;colsq[i]=0.f;}
}

__global__ __launch_bounds__(256) void k_deg(const int* __restrict__ ei,const float* __restrict__ ew,
                                             float* deg,int* cnt){
  int e=blockIdx.x*256+threadIdx.x;
  if(e<NE){int d=ei[NE+e];atomicAdd(&deg[d],ew[e]);atomicAdd(&cnt[d],1);}
}

__global__ __launch_bounds__(256) void k_dinv(const float* __restrict__ deg,float* dinv){
  int i=blockIdx.x*256+threadIdx.x;
  if(i<NN){float d=deg[i];dinv[i]=d>0.f?rsqrtf(d):0.f;}
}

__global__ __launch_bounds__(1024) void k_scan(const int* __restrict__ cnt,int* row_ptr,int* cursor){
  __shared__ int s[1024];
  __shared__ int carry;
  int tid=threadIdx.x;
  if(tid==0)carry=0;
  __syncthreads();
  for(int base=0;base<NN;base+=1024){
    int i=base+tid;
    int v=(i<NN)?cnt[i]:0;
    s[tid]=v;__syncthreads();
    for(int off=1;off<1024;off<<=1){
      int t=(tid>=off)?s[tid-off]:0;
      __syncthreads();
      s[tid]+=t;__syncthreads();
    }
    int excl=carry+s[tid]-v;
    if(i<NN){row_ptr[i]=excl;cursor[i]=excl;}
    __syncthreads();
    if(tid==1023)carry+=s[1023];
    __syncthreads();
  }
  if(tid==0)row_ptr[NN]=carry;
}

__global__ __launch_bounds__(256) void k_scatter(const int* __restrict__ ei,const float* __restrict__ ew,
    const float* __restrict__ dinv,int* cursor,int* csr_src,float* csr_w){
  int e=blockIdx.x*256+threadIdx.x;
  if(e<NE){
    int s=ei[e],d=ei[NE+e];
    float wv=dinv[s]*ew[e]*dinv[d];
    int p=atomicAdd(&cursor[d],1);
    csr_src[p]=s;csr_w[p]=wv;
  }
}

// ---------- weight prep ----------
__global__ __launch_bounds__(256) void k_wt(const float* __restrict__ W,unsigned short* __restrict__ Wt){
  int j=blockIdx.x,k=threadIdx.x;
  Wt[j*256+k]=f2b(W[k*256+j]);
}
__global__ __launch_bounds__(256) void k_f2b(const float* __restrict__ s,unsigned short* __restrict__ d,int n){
  int i=blockIdx.x*256+threadIdx.x;
  if(i<n)d[i]=f2b(s[i]);
}
__global__ __launch_bounds__(256) void k_bsum(const float* __restrict__ a,const float* __restrict__ b,
                                              float* __restrict__ s,int n){
  int i=blockIdx.x*256+threadIdx.x;
  if(i<n)s[i]=a[i]+b[i];
}

// ---------- dense MFMA GEMM: Cb[M,256](bf16) = A[M,K] @ Bt^T  (Bt is [256][K] bf16) ----------
template<typename TA>
__global__ __launch_bounds__(256,2) void k_gemm_mfma(
    const TA* __restrict__ A,int lda,const unsigned short* __restrict__ Bt,int K,
    unsigned short* __restrict__ Cb){
  __shared__ unsigned short As[128*LDP];
  __shared__ unsigned short Bs[128*LDP];
  int tid=threadIdx.x;
  int row0=blockIdx.x*128,col0=blockIdx.y*128;
  int lane=tid&63,l15=lane&15,quad=lane>>4;
  int wid=tid>>6,wm=wid>>1,wn=wid&1;
  f32x4 acc[4][4]={};
  for(int k0=0;k0<K;k0+=32){
    if constexpr(sizeof(TA)==4){
      int r=tid>>3,ks=(tid&7)*4;
      #pragma unroll
      for(int rr=0;rr<4;rr++){
        int row=row0+rr*32+r;
        float4 v=make_float4(0.f,0.f,0.f,0.f);
        if(row<NN)v=*(const float4*)&A[(long)row*lda+k0+ks];
        ushort4 h;h.x=f2b(v.x);h.y=f2b(v.y);h.z=f2b(v.z);h.w=f2b(v.w);
        *(ushort4*)&As[(rr*32+r)*LDP+ks]=h;
      }
    }else{
      int r=tid>>2,ks=(tid&3)*8;
      #pragma unroll
      for(int rr=0;rr<2;rr++){
        int row=row0+rr*64+r;
        bf8 v=(bf8)(short)0;
        if(row<NN)v=*(const bf8*)&A[(long)row*lda+k0+ks];
        *(bf8*)&As[(rr*64+r)*LDP+ks]=v;
      }
    }
    { int r=tid>>2,ks=(tid&3)*8;
      #pragma unroll
      for(int rr=0;rr<2;rr++){
        bf8 v=*(const bf8*)&Bt[(long)(col0+rr*64+r)*K+k0+ks];
        *(bf8*)&Bs[(rr*64+r)*LDP+ks]=v;
      }
    }
    __syncthreads();
    bf8 af[4],bfg[4];
    #pragma unroll
    for(int i=0;i<4;i++){
      af[i]=*(const bf8*)&As[(wm*64+i*16+l15)*LDP+quad*8];
      bfg[i]=*(const bf8*)&Bs[(wn*64+i*16+l15)*LDP+quad*8];
    }
    #pragma unroll
    for(int mi=0;mi<4;mi++)
      #pragma unroll
      for(int ni=0;ni<4;ni++)
        acc[mi][ni]=__builtin_amdgcn_mfma_f32_16x16x32_bf16(af[mi],bfg[ni],acc[mi][ni],0,0,0);
    __syncthreads();
  }
  #pragma unroll
  for(int mi=0;mi<4;mi++){
    #pragma unroll
    for(int r=0;r<4;r++){
      int node=row0+wm*64+mi*16+quad*4+r;
      if(node>=NN)continue;
      #pragma unroll
      for(int ni=0;ni<4;ni++){
        int col=col0+wn*64+ni*16+l15;
        Cb[(long)node*256+col]=f2b(acc[mi][ni][r]);
      }
    }
  }
}

// ---------- fused 3-gate LSTM MFMA: h = sig(o)*tanh(sig(i)*tanh(g)) ----------
__global__ __launch_bounds__(256,2) void k_lstm_mfma(
    const unsigned short* __restrict__ A,int lda,int K,
    const unsigned short* __restrict__ Wb,const float* __restrict__ bsum,
    float* __restrict__ Hout,int ldh,unsigned short* __restrict__ Hb){
  __shared__ unsigned short As[128*LDP];
  __shared__ unsigned short Bs[3*64*LDP];
  int tid=threadIdx.x;
  int row0=blockIdx.x*128,m0=blockIdx.y*64;
  int lane=tid&63,l15=lane&15,quad=lane>>4;
  int wid=tid>>6,wm=wid>>1,wn=wid&1;
  f32x4 ai[4][2]={},ag[4][2]={},ao[4][2]={};
  for(int k0=0;k0<K;k0+=32){
    { int r=tid>>2,ks=(tid&3)*8;
      #pragma unroll
      for(int rr=0;rr<2;rr++){
        int row=row0+rr*64+r;
        bf8 v=(bf8)(short)0;
        if(row<NN)v=*(const bf8*)&A[(long)row*lda+k0+ks];
        *(bf8*)&As[(rr*64+r)*LDP+ks]=v;
      }
      bf8 v0=*(const bf8*)&Wb[(long)(  0+m0+r)*K+k0+ks];
      bf8 v1=*(const bf8*)&Wb[(long)(512+m0+r)*K+k0+ks];
      bf8 v2=*(const bf8*)&Wb[(long)(768+m0+r)*K+k0+ks];
      *(bf8*)&Bs[(0*64+r)*LDP+ks]=v0;
      *(bf8*)&Bs[(1*64+r)*LDP+ks]=v1;
      *(bf8*)&Bs[(2*64+r)*LDP+ks]=v2;
    }
    __syncthreads();
    bf8 af[4],bi[2],bg[2],bo[2];
    #pragma unroll
    for(int i=0;i<4;i++)af[i]=*(const bf8*)&As[(wm*64+i*16+l15)*LDP+quad*8];
    #pragma unroll
    for(int ni=0;ni<2;ni++){
      int rr=wn*32+ni*16+l15;
      bi[ni]=*(const bf8*)&Bs[(0*64+rr)*LDP+quad*8];
      bg[ni]=*(const bf8*)&Bs[(1*64+rr)*LDP+quad*8];
      bo[ni]=*(const bf8*)&Bs[(2*64+rr)*LDP+quad*8];
    }
    #pragma unroll
    for(int mi=0;mi<4;mi++)
      #pragma unroll
      for(int ni=0;ni<2;ni++){
        ai[mi][ni]=__builtin_amdgcn_mfma_f32_16x16x32_bf16(af[mi],bi[ni],ai[mi][ni],0,0,0);
        ag[mi][ni]=__builtin_amdgcn_mfma_f32_16x16x32_bf16(af[mi],bg[ni],ag[mi][ni],0,0,0);
        ao[mi][ni]=__builtin_amdgcn_mfma_f32_16x16x32_bf16(af[mi],bo[ni],ao[mi][ni],0,0,0);
      }
    __syncthreads();
  }
  #pragma unroll
  for(int ni=0;ni<2;ni++){
    int m=m0+wn*32+ni*16+l15;
    float b_i=bsum[m],b_g=bsum[512+m],b_o=bsum[768+m];
    #pragma unroll
    for(int mi=0;mi<4;mi++){
      #pragma unroll
      for(int r=0;r<4;r++){
        int node=row0+wm*64+mi*16+quad*4+r;
        if(node>=NN)continue;
        float gi=ai[mi][ni][r]+b_i;
        float gg=ag[mi][ni][r]+b_g;
        float go=ao[mi][ni][r]+b_o;
        float c=sigm(gi)*tanhf(gg);
        float h=sigm(go)*tanhf(c);
        Hout[(long)node*ldh+m]=h;
        if(Hb)Hb[(long)node*256+m]=f2b(h);
      }
    }
  }
}

// ---------- SpMM (bf16 T) + self-loop + bias + ReLU + stats; wave-per-row, ILP-2 ----------
// Tb: bf16 [N,256]. Output: pre-BN bf16 into Xb (ld 512). Block=4 waves, 8 rows/wave, 32 rows/block.
__global__ __launch_bounds__(256) void k_spmm(const unsigned short* __restrict__ Tb,
    const int* __restrict__ row_ptr,const int* __restrict__ csr_src,const float* __restrict__ csr_w,
    const float* __restrict__ dinv,const float* __restrict__ bias,
    unsigned short* __restrict__ Xb,float* colsum,float* colsq){
  __shared__ float s_sum[4][256];
  __shared__ float s_sq[4][256];
  int tid=threadIdx.x;
  int lane=tid&63,wv=tid>>6;
  int c4=lane*4;
  float4 bc=*(const float4*)&bias[c4];
  float sum0=0.f,sum1=0.f,sum2=0.f,sum3=0.f;
  float sq0=0.f,sq1=0.f,sq2=0.f,sq3=0.f;
  int rowbase=blockIdx.x*32+wv*8;
  #pragma unroll 1
  for(int pr=0;pr<4;pr++){
    int ra=rowbase+pr*2,rb=ra+1;
    bool va=ra<NN,vb=rb<NN;
    int raa=va?ra:0,rbb=vb?rb:0;
    int p0a=row_ptr[raa],p1a=row_ptr[raa+1];
    int p0b=row_ptr[rbb],p1b=row_ptr[rbb+1];
    int la=va?(p1a-p0a):0,lb=vb?(p1b-p0b):0;
    float dia=dinv[raa],dib=dinv[rbb];
    // self-loop init
    ushort4 tsa=*(const ushort4*)&Tb[(long)raa*256+c4];
    ushort4 tsb=*(const ushort4*)&Tb[(long)rbb*256+c4];
    float wsa=dia*dia,wsb=dib*dib;
    float a0=wsa*b2f(tsa.x),a1=wsa*b2f(tsa.y),a2=wsa*b2f(tsa.z),a3=wsa*b2f(tsa.w);
    float b0=wsb*b2f(tsb.x),b1=wsb*b2f(tsb.y),b2=wsb*b2f(tsb.z),b3=wsb*b2f(tsb.w);
    int L=max(la,lb);
    for(int j=0;j<L;j++){
      int ia=j<la?(p0a+j):p0a;
      int ib=j<lb?(p0b+j):p0b;
      float wa=j<la?csr_w[ia]:0.f;
      float wb=j<lb?csr_w[ib]:0.f;
      int sa=csr_src[ia];sa=min(max(sa,0),NN-1);
      int sb=csr_src[ib];sb=min(max(sb,0),NN-1);
      ushort4 ta=*(const ushort4*)&Tb[(long)sa*256+c4];
      ushort4 tb=*(const ushort4*)&Tb[(long)sb*256+c4];
      a0+=wa*b2f(ta.x);a1+=wa*b2f(ta.y);a2+=wa*b2f(ta.z);a3+=wa*b2f(ta.w);
      b0+=wb*b2f(tb.x);b1+=wb*b2f(tb.y);b2+=wb*b2f(tb.z);b3+=wb*b2f(tb.w);
    }
    if(va){
      a0=fmaxf(a0+bc.x,0.f);a1=fmaxf(a1+bc.y,0.f);a2=fmaxf(a2+bc.z,0.f);a3=fmaxf(a3+bc.w,0.f);
      ushort4 o;o.x=f2b(a0);o.y=f2b(a1);o.z=f2b(a2);o.w=f2b(a3);
      *(ushort4*)&Xb[(long)ra*512+c4]=o;
      sum0+=a0;sum1+=a1;sum2+=a2;sum3+=a3;
      sq0+=a0*a0;sq1+=a1*a1;sq2+=a2*a2;sq3+=a3*a3;
    }
    if(vb){
      b0=fmaxf(b0+bc.x,0.f);b1=fmaxf(b1+bc.y,0.f);b2=fmaxf(b2+bc.z,0.f);b3=fmaxf(b3+bc.w,0.f);
      ushort4 o;o.x=f2b(b0);o.y=f2b(b1);o.z=f2b(b2);o.w=f2b(b3);
      *(ushort4*)&Xb[(long)rb*512+c4]=o;
      sum0+=b0;sum1+=b1;sum2+=b2;sum3+=b3;
      sq0+=b0*b0;sq1+=b1*b1;sq2+=b2*b2;sq3+=b3*b3;
    }
  }
  s_sum[wv][c4+0]=sum0;s_sum[wv][c4+1]=sum1;s_sum[wv][c4+2]=sum2;s_sum[wv][c4+3]=sum3;
  s_sq[wv][c4+0]=sq0;s_sq[wv][c4+1]=sq1;s_sq[wv][c4+2]=sq2;s_sq[wv][c4+3]=sq3;
  __syncthreads();
  if(tid<256){
    float a=s_sum[0][tid]+s_sum[1][tid]+s_sum[2][tid]+s_sum[3][tid];
    float q=s_sq[0][tid]+s_sq[1][tid]+s_sq[2][tid]+s_sq[3][tid];
    atomicAdd(&colsum[tid],a);
    atomicAdd(&colsq[tid],q);
  }
}

__global__ __launch_bounds__(256) void k_bnfin(const float* __restrict__ gamma,const float* __restrict__ beta,
    float* colsum,float* colsq,float* scale,float* shift){
  int c=threadIdx.x;
  float mu=colsum[c]/(float)NN;
  float var=colsq[c]/(float)NN-mu*mu;
  float r=rsqrtf(var+1e-5f);
  float sc=r*gamma[c];
  scale[c]=sc;
  shift[c]=beta[c]-mu*sc;
  colsum[c]=0.f;colsq[c]=0.f;
}

// BN affine in place on bf16 slab (ld 512)
__global__ __launch_bounds__(256) void k_bnapply(unsigned short* __restrict__ Xb,
    const float* __restrict__ scale,const float* __restrict__ shift){
  long idx=(long)blockIdx.x*256+threadIdx.x;
  long r=idx>>6;int c=(int)(idx&63)*4;
  if(r<NN){
    ushort4 v=*(const ushort4*)&Xb[r*512+c];
    ushort4 w;
    w.x=f2b(b2f(v.x)*scale[c+0]+shift[c+0]);
    w.y=f2b(b2f(v.y)*scale[c+1]+shift[c+1]);
    w.z=f2b(b2f(v.z)*scale[c+2]+shift[c+2]);
    w.w=f2b(b2f(v.w)*scale[c+3]+shift[c+3]);
    *(ushort4*)&Xb[r*512+c]=w;
  }
}

// copy [N,256] fp32 (ld 256) into out columns [colofs, colofs+256)
__global__ __launch_bounds__(256) void k_copy_out(const float* __restrict__ src,
    float* __restrict__ out,int colofs){
  long idx=(long)blockIdx.x*256+threadIdx.x;
  long r=idx>>6;int cc=(int)(idx&63)*4;
  if(r<NN)*(float4*)&out[r*768+colofs+cc]=*(const float4*)&src[r*256+cc];
}

extern "C" void kernel_launch(void* const* d_in,const int* in_sizes,int n_in,
                              void* d_out,int out_size,void* d_ws,size_t ws_size,
                              hipStream_t stream){
  const float* x   =(const float*)d_in[0];
  const int*   ei  =(const int*)  d_in[1];
  const float* ew  =(const float*)d_in[2];
  const float* W1  =(const float*)d_in[3];
  const float* b1  =(const float*)d_in[4];
  const float* W2  =(const float*)d_in[5];
  const float* b2  =(const float*)d_in[6];
  const float* g1  =(const float*)d_in[7];
  const float* be1 =(const float*)d_in[8];
  const float* g2  =(const float*)d_in[9];
  const float* be2 =(const float*)d_in[10];
  const float* Wih1=(const float*)d_in[11];
  const float* bih1=(const float*)d_in[13];
  const float* bhh1=(const float*)d_in[14];
  const float* Wih2=(const float*)d_in[15];
  const float* bih2=(const float*)d_in[17];
  const float* bhh2=(const float*)d_in[18];
  float* out=(float*)d_out;

  char* w=(char*)d_ws;
  auto alloc=[&](size_t bytes)->char*{char* p=w;w+=(bytes+255)&~(size_t)255;return p;};
  float* deg    =(float*)alloc((size_t)NN*4);
  float* dinv   =(float*)alloc((size_t)NN*4);
  int*   cnt    =(int*)  alloc((size_t)NN*4);
  int*   row_ptr=(int*)  alloc((size_t)(NN+1)*4);
  int*   cursor =(int*)  alloc((size_t)NN*4);
  int*   csr_src=(int*)  alloc((size_t)NE*4);
  float* csr_w  =(float*)alloc((size_t)NE*4);
  float* colsum =(float*)alloc(256*4);
  float* colsq  =(float*)alloc(256*4);
  float* scale  =(float*)alloc(256*4);
  float* shift  =(float*)alloc(256*4);
  unsigned short* Xcb =(unsigned short*)alloc((size_t)NN*512*2);  // [h1n|h2n] bf16, ld 512
  unsigned short* TbH =(unsigned short*)alloc((size_t)NN*256*2);  // GEMM out / LSTM1 hidden (aliased)
  unsigned short* Wt1 =(unsigned short*)alloc(256*256*2);
  unsigned short* Wt2 =(unsigned short*)alloc(256*256*2);
  unsigned short* Wb1 =(unsigned short*)alloc((size_t)1024*512*2);
  unsigned short* Wb2 =(unsigned short*)alloc((size_t)1024*256*2);
  float* bs1 =(float*)alloc(1024*4);
  float* bs2 =(float*)alloc(1024*4);

  int nb=(NN+255)/256;
  k_init<<<nb,256,0,stream>>>(deg,cnt,colsum,colsq);
  k_deg<<<(NE+255)/256,256,0,stream>>>(ei,ew,deg,cnt);
  k_dinv<<<nb,256,0,stream>>>(deg,dinv);
  k_scan<<<1,1024,0,stream>>>(cnt,row_ptr,cursor);
  k_scatter<<<(NE+255)/256,256,0,stream>>>(ei,ew,dinv,cursor,csr_src,csr_w);

  k_wt<<<256,256,0,stream>>>(W1,Wt1);
  k_wt<<<256,256,0,stream>>>(W2,Wt2);
  k_f2b<<<(1024*512+255)/256,256,0,stream>>>(Wih1,Wb1,1024*512);
  k_f2b<<<(1024*256+255)/256,256,0,stream>>>(Wih2,Wb2,1024*256);
  k_bsum<<<4,256,0,stream>>>(bih1,bhh1,bs1,1024);
  k_bsum<<<4,256,0,stream>>>(bih2,bhh2,bs2,1024);

  int ngx=(NN+127)/128;
  dim3 gd(ngx,2);   // dense GEMM: 256 cols / 128
  dim3 gl(ngx,4);   // lstm: 256 h-cols / 64
  int nspmm=(NN+31)/32;

  // layer 1
  k_gemm_mfma<float><<<gd,256,0,stream>>>(x,256,Wt1,256,TbH);
  k_spmm<<<nspmm,256,0,stream>>>(TbH,row_ptr,csr_src,csr_w,dinv,b1,Xcb+0,colsum,colsq);
  k_bnfin<<<1,256,0,stream>>>(g1,be1,colsum,colsq,scale,shift);
  k_bnapply<<<12500,256,0,stream>>>(Xcb+0,scale,shift);
  // layer 2
  k_gemm_mfma<unsigned short><<<gd,256,0,stream>>>(Xcb,512,Wt2,256,TbH);
  k_spmm<<<nspmm,256,0,stream>>>(TbH,row_ptr,csr_src,csr_w,dinv,b2,Xcb+256,colsum,colsq);
  k_bnfin<<<1,256,0,stream>>>(g2,be2,colsum,colsq,scale,shift);
  k_bnapply<<<12500,256,0,stream>>>(Xcb+256,scale,shift);
  // LSTM1: A=Xcb [N,512] -> out[0:256) fp32 + TbH bf16 (TbH dead after spmm2)
  k_lstm_mfma<<<gl,256,0,stream>>>(Xcb,512,512,Wb1,bs1,out+0,768,TbH);
  // LSTM2: A=TbH [N,256] -> out[256:512)
  k_lstm_mfma<<<gl,256,0,stream>>>(TbH,256,256,Wb2,bs2,out+256,768,nullptr);
  // x passthrough
  k_copy_out<<<12500,256,0,stream>>>(x,out,512);
}